// Round 2
// baseline (184.585 us; speedup 1.0000x reference)
//
#include <hip/hip_runtime.h>
#include <math.h>

#define N_QUBITS 6
#define N_LAYERS 3

// Each thread processes 2 batch rows = 12 floats = 3 x float4 (48 B aligned).
__global__ __launch_bounds__(256) void qc_kernel(
    const float* __restrict__ x,
    const float* __restrict__ rot,   // (N_LAYERS, N_QUBITS, 3)
    const float* __restrict__ ent,   // (N_LAYERS, N_QUBITS-1)
    float* __restrict__ out,
    int n_pairs)
{
    // Per-block constant tables in LDS: cos(rx/2), sin(rx/2), sigmoid(ent)
    __shared__ float sc[N_LAYERS][N_QUBITS];
    __shared__ float ss[N_LAYERS][N_QUBITS];
    __shared__ float sst[N_LAYERS][N_QUBITS - 1];

    const int t = threadIdx.x;
    if (t < N_LAYERS * N_QUBITS) {                       // threads 0..17
        const int l = t / N_QUBITS, q = t % N_QUBITS;
        const float rx = rot[(l * N_QUBITS + q) * 3 + 0];
        float s_, c_;
        sincosf(rx * 0.5f, &s_, &c_);
        sc[l][q] = c_;
        ss[l][q] = s_;
    } else if (t < N_LAYERS * N_QUBITS + N_LAYERS * (N_QUBITS - 1)) {  // 18..32
        const int u = t - N_LAYERS * N_QUBITS;
        const int l = u / (N_QUBITS - 1), j = u % (N_QUBITS - 1);
        const float e = ent[l * (N_QUBITS - 1) + j];
        sst[l][j] = 1.0f / (1.0f + expf(-e));
    }
    __syncthreads();

    const int idx = blockIdx.x * blockDim.x + threadIdx.x;
    if (idx >= n_pairs) return;

    const float4* __restrict__ xin = (const float4*)(x + (size_t)idx * 12);
    float4 va = xin[0];
    float4 vb = xin[1];
    float4 vc = xin[2];
    float v[12] = {va.x, va.y, va.z, va.w,
                   vb.x, vb.y, vb.z, vb.w,
                   vc.x, vc.y, vc.z, vc.w};
    float o[12];

#pragma unroll
    for (int r0 = 0; r0 < 2; ++r0) {
        float re[N_QUBITS], im[N_QUBITS];
#pragma unroll
        for (int q = 0; q < N_QUBITS; ++q) {
            const float h = v[r0 * 6 + q] * 1.5707963267948966f;  // x * pi/2
            sincosf(h, &im[q], &re[q]);   // imag = sin, real = cos
        }
#pragma unroll
        for (int l = 0; l < N_LAYERS; ++l) {
            // per-qubit rotation (mixes re/im)
#pragma unroll
            for (int q = 0; q < N_QUBITS; ++q) {
                const float c_ = sc[l][q], s_ = ss[l][q];
                const float nr = c_ * re[q] + s_ * im[q];
                const float ni = c_ * im[q] - s_ * re[q];
                re[q] = nr;
                im[q] = ni;
            }
            // entanglement mixing on re[] only — mirror reference FP association
            float avg[N_QUBITS - 1];
#pragma unroll
            for (int j = 0; j < N_QUBITS - 1; ++j)
                avg[j] = (re[j] + re[j + 1]) * 0.5f;
            float nr_[N_QUBITS];
#pragma unroll
            for (int j = 0; j < N_QUBITS - 1; ++j) {
                const float st = sst[l][j];
                nr_[j] = (1.0f - st) * re[j] + st * avg[j];
            }
            {
                const float st = sst[l][N_QUBITS - 2];
                nr_[N_QUBITS - 1] =
                    (1.0f - st) * re[N_QUBITS - 1] + st * avg[N_QUBITS - 2];
            }
#pragma unroll
            for (int q = 0; q < N_QUBITS; ++q) re[q] = nr_[q];
        }
#pragma unroll
        for (int q = 0; q < N_QUBITS; ++q)
            o[r0 * 6 + q] = sqrtf(re[q] * re[q] + im[q] * im[q]);
    }

    float4* __restrict__ dst = (float4*)(out + (size_t)idx * 12);
    dst[0] = make_float4(o[0], o[1], o[2], o[3]);
    dst[1] = make_float4(o[4], o[5], o[6], o[7]);
    dst[2] = make_float4(o[8], o[9], o[10], o[11]);
}

extern "C" void kernel_launch(void* const* d_in, const int* in_sizes, int n_in,
                              void* d_out, int out_size, void* d_ws, size_t ws_size,
                              hipStream_t stream) {
    const float* x   = (const float*)d_in[0];
    const float* rot = (const float*)d_in[1];
    const float* ent = (const float*)d_in[2];
    float* out = (float*)d_out;

    const int n_rows  = in_sizes[0] / N_QUBITS;   // 4194304
    const int n_pairs = n_rows / 2;               // 2097152 (even batch)
    const int block = 256;
    const int grid = (n_pairs + block - 1) / block;  // 8192

    qc_kernel<<<grid, block, 0, stream>>>(x, rot, ent, out, n_pairs);
}

// Round 3
// 182.017 us; speedup vs baseline: 1.0141x; 1.0141x over previous
//
#include <hip/hip_runtime.h>
#include <math.h>

#define N_QUBITS 6
#define N_LAYERS 3

// Each thread processes 2 batch rows = 12 floats = 3 x float4 (48 B aligned).
__global__ __launch_bounds__(256) void qc_kernel(
    const float* __restrict__ x,
    const float* __restrict__ rot,   // (N_LAYERS, N_QUBITS, 3)
    const float* __restrict__ ent,   // (N_LAYERS, N_QUBITS-1)
    float* __restrict__ out,
    int n_pairs)
{
    // Per-block constant tables in LDS: cos(rx/2), sin(rx/2), sigmoid(ent)
    __shared__ float sc[N_LAYERS][N_QUBITS];
    __shared__ float ss[N_LAYERS][N_QUBITS];
    __shared__ float sst[N_LAYERS][N_QUBITS - 1];

    const int t = threadIdx.x;
    if (t < N_LAYERS * N_QUBITS) {                       // threads 0..17
        const int l = t / N_QUBITS, q = t % N_QUBITS;
        const float rx = rot[(l * N_QUBITS + q) * 3 + 0];
        float s_, c_;
        sincosf(rx * 0.5f, &s_, &c_);   // once per block; keep libm accuracy
        sc[l][q] = c_;
        ss[l][q] = s_;
    } else if (t < N_LAYERS * N_QUBITS + N_LAYERS * (N_QUBITS - 1)) {  // 18..32
        const int u = t - N_LAYERS * N_QUBITS;
        const int l = u / (N_QUBITS - 1), j = u % (N_QUBITS - 1);
        const float e = ent[l * (N_QUBITS - 1) + j];
        sst[l][j] = 1.0f / (1.0f + expf(-e));
    }
    __syncthreads();

    const int idx = blockIdx.x * blockDim.x + threadIdx.x;
    if (idx >= n_pairs) return;

    const float4* __restrict__ xin = (const float4*)(x + (size_t)idx * 12);
    float4 va = xin[0];
    float4 vb = xin[1];
    float4 vc = xin[2];
    float v[12] = {va.x, va.y, va.z, va.w,
                   vb.x, vb.y, vb.z, vb.w,
                   vc.x, vc.y, vc.z, vc.w};
    float o[12];

#pragma unroll
    for (int r0 = 0; r0 < 2; ++r0) {
        float re[N_QUBITS], im[N_QUBITS];
#pragma unroll
        for (int q = 0; q < N_QUBITS; ++q) {
            // sin/cos(x*pi/2): x in [0,1) -> x/4 revolutions in [0,0.25).
            // v_sin_f32/v_cos_f32 take REVOLUTIONS; no range reduction needed.
            const float rev = v[r0 * 6 + q] * 0.25f;
            im[q] = __builtin_amdgcn_sinf(rev);
            re[q] = __builtin_amdgcn_cosf(rev);
        }
#pragma unroll
        for (int l = 0; l < N_LAYERS; ++l) {
            // per-qubit rotation (mixes re/im)
#pragma unroll
            for (int q = 0; q < N_QUBITS; ++q) {
                const float c_ = sc[l][q], s_ = ss[l][q];
                const float nr = c_ * re[q] + s_ * im[q];
                const float ni = c_ * im[q] - s_ * re[q];
                re[q] = nr;
                im[q] = ni;
            }
            // entanglement mixing on re[] only — mirror reference FP association
            float avg[N_QUBITS - 1];
#pragma unroll
            for (int j = 0; j < N_QUBITS - 1; ++j)
                avg[j] = (re[j] + re[j + 1]) * 0.5f;
            float nr_[N_QUBITS];
#pragma unroll
            for (int j = 0; j < N_QUBITS - 1; ++j) {
                const float st = sst[l][j];
                nr_[j] = (1.0f - st) * re[j] + st * avg[j];
            }
            {
                const float st = sst[l][N_QUBITS - 2];
                nr_[N_QUBITS - 1] =
                    (1.0f - st) * re[N_QUBITS - 1] + st * avg[N_QUBITS - 2];
            }
#pragma unroll
            for (int q = 0; q < N_QUBITS; ++q) re[q] = nr_[q];
        }
#pragma unroll
        for (int q = 0; q < N_QUBITS; ++q)
            o[r0 * 6 + q] = sqrtf(re[q] * re[q] + im[q] * im[q]);
    }

    float4* __restrict__ dst = (float4*)(out + (size_t)idx * 12);
    dst[0] = make_float4(o[0], o[1], o[2], o[3]);
    dst[1] = make_float4(o[4], o[5], o[6], o[7]);
    dst[2] = make_float4(o[8], o[9], o[10], o[11]);
}

extern "C" void kernel_launch(void* const* d_in, const int* in_sizes, int n_in,
                              void* d_out, int out_size, void* d_ws, size_t ws_size,
                              hipStream_t stream) {
    const float* x   = (const float*)d_in[0];
    const float* rot = (const float*)d_in[1];
    const float* ent = (const float*)d_in[2];
    float* out = (float*)d_out;

    const int n_rows  = in_sizes[0] / N_QUBITS;   // 4194304
    const int n_pairs = n_rows / 2;               // 2097152 (even batch)
    const int block = 256;
    const int grid = (n_pairs + block - 1) / block;  // 8192

    qc_kernel<<<grid, block, 0, stream>>>(x, rot, ent, out, n_pairs);
}